// Round 13
// baseline (175.933 us; speedup 1.0000x reference)
//
#include <hip/hip_runtime.h>
#include <math.h>

#define BB 8
#define NN 1024
#define MM 256
#define BETA 8
#define M1 16
#define NFEAT 64
#define HH 128
#define NTOT 1088   /* N + NGHOST */
#define F3 (NTOT*3) /* 3264 */
#define RMINf 0.5f
#define SPANf 5.5f
#define PIf 3.14159265358979323846f

#define OUT_EI 8
#define OUT_FORCE 8200          /* 8 + 8192 */
#define OUT_VIR 34312           /* 8200 + 8*1088*3 */

#define NG2 128                 /* scatter/bwd groups per batch (round-8 optimum) */
#define AT2 (NN/NG2)            /* 8 atoms per fused block */

#define MT 16                   /* atoms per MLP tile */
#define AS0 68                  /* xb stride (64+4), 16B-aligned rows */
#define AS1 132                 /* activation stride (128+4), 16B-aligned rows */

/* workspace float offsets */
#define WS_S     0
#define WS_DF    (WS_S + 8192*64)
#define WS_FP    (WS_DF + 8192*64)       /* fpart partials: 1024*F3 */
#define WS_STATP (WS_FP + BB*NG2*F3)
#define WS_VIRP  (WS_STATP + 8192*2)     /* 1024*9 */
#define WS_WTB   (WS_VIRP + BB*NG2*9)    /* bf16 transposed weights: 81920 shorts */
#define WS_WB    (WS_WTB + 40960)        /* bf16 original weights: 81920 shorts */
#define WT0_OFF  0
#define WT1_OFF  16384
#define WT2_OFF  49152

typedef __attribute__((ext_vector_type(8))) short bf8;
typedef __attribute__((ext_vector_type(4))) float f4;

__device__ __forceinline__ float ftanh(float x) {
  const float e = __expf(2.0f*x);
  return 1.0f - 2.0f/(e + 1.0f);
}
__device__ __forceinline__ short f2bs(float f) {   /* fp32 -> bf16 RNE */
  unsigned u = __float_as_uint(f);
  return (short)((u + 0x7FFFu + ((u >> 16) & 1u)) >> 16);
}
__device__ __forceinline__ bf8 a_frag(const float* p) {  /* 8 consecutive fp32 -> bf16x8 */
  bf8 a;
  #pragma unroll
  for (int i = 0; i < 8; ++i) a[i] = f2bs(p[i]);
  return a;
}
__device__ __forceinline__ f4 splat4(float v) {
  f4 r; r[0] = v; r[1] = v; r[2] = v; r[3] = v; return r;
}
/* wave64 sum via DPP (VALU pipe, no LDS); total lands in lane 63 */
__device__ __forceinline__ float dpp_wave_sum(float x) {
  x += __int_as_float(__builtin_amdgcn_update_dpp(0, __float_as_int(x), 0x111, 0xf, 0xf, true));
  x += __int_as_float(__builtin_amdgcn_update_dpp(0, __float_as_int(x), 0x112, 0xf, 0xf, true));
  x += __int_as_float(__builtin_amdgcn_update_dpp(0, __float_as_int(x), 0x114, 0xf, 0xf, true));
  x += __int_as_float(__builtin_amdgcn_update_dpp(0, __float_as_int(x), 0x118, 0xf, 0xf, true));
  x += __int_as_float(__builtin_amdgcn_update_dpp(0, __float_as_int(x), 0x142, 0xf, 0xf, true));
  x += __int_as_float(__builtin_amdgcn_update_dpp(0, __float_as_int(x), 0x143, 0xf, 0xf, true));
  return x;
}

/* ---- features: DPP wave reduction (no prod array; LDS 39KB -> ~5KB) ---- */
__global__ __launch_bounds__(256) void k_feat(
    const float* __restrict__ rvec, const int* __restrict__ tmap,
    const float* __restrict__ c_param, float* __restrict__ S_ws,
    float* __restrict__ statp,
    const float* __restrict__ W0, const float* __restrict__ W1,
    const float* __restrict__ W2,
    unsigned short* __restrict__ wtb, unsigned short* __restrict__ wb)
{
  __shared__ float rv[768];
  __shared__ float c_lds[256];
  __shared__ float part[4*32];
  __shared__ float U[2*32];
  __shared__ float S_lds[64];
  const int tid = threadIdx.x;
  if (blockIdx.x >= BB*NN) {
    const int idx = (blockIdx.x - BB*NN)*256 + tid;  /* 0..163839 */
    if (idx < 81920) {
      unsigned short v;
      if (idx < 16384) {
        const int t = idx >> 13, rem = idx & 8191;
        const int j = rem >> 6, f = rem & 63;
        v = (unsigned short)f2bs(W0[t*8192 + f*128 + j]);
      } else if (idx < 49152) {
        const int i = idx - 16384;
        const int t = i >> 14, rem = i & 16383;
        const int j = rem >> 7, f = rem & 127;
        v = (unsigned short)f2bs(W1[t*16384 + f*128 + j]);
      } else {
        const int i = idx - 49152;
        const int t = i >> 14, rem = i & 16383;
        const int j = rem >> 7, f = rem & 127;
        v = (unsigned short)f2bs(W2[t*16384 + f*128 + j]);
      }
      wtb[idx] = v;
    } else {
      const int k = idx - 81920;
      float src;
      if (k < 16384) src = W0[k];
      else if (k < 49152) src = W1[k - 16384];
      else src = W2[k - 49152];
      wb[k] = (unsigned short)f2bs(src);
    }
    return;
  }
  const int bn = blockIdx.x;
  const int n = bn & (NN-1);
  const int ti = tmap[n];
  c_lds[tid] = c_param[ti*256 + tid];
  const float* rb = rvec + (size_t)bn*MM*3;
  rv[tid] = rb[tid]; rv[tid+256] = rb[tid+256]; rv[tid+512] = rb[tid+512];
  __syncthreads();
  const int m = tid;
  const int wave = tid >> 6, lane = tid & 63;
  const float x = rv[3*m], y = rv[3*m+1], z = rv[3*m+2];
  const float r = sqrtf(x*x + y*y + z*z);
  const float inv_r = 1.0f / r;
  const float ux = x*inv_r, uy = y*inv_r, uz = z*inv_r;
  float u = 2.0f*(r - RMINf)/SPANf - 1.0f;
  u = fminf(fmaxf(u, -1.0f), 1.0f);
  const float fc = 0.5f*(__cosf(PIf*(r - RMINf)/SPANf) + 1.0f);
  float T[BETA];
  T[0] = 1.0f; T[1] = u;
  #pragma unroll
  for (int k = 2; k < BETA; ++k) T[k] = 2.0f*u*T[k-1] - T[k-2];
  /* wave-level reduction of fc*T_k*q_a: waves 0,1 = tj0 (m<128), 2,3 = tj1 */
  #pragma unroll
  for (int k = 0; k < BETA; ++k) {
    const float ft = fc*T[k];
    const float v0 = dpp_wave_sum(ft);
    const float v1 = dpp_wave_sum(ft*ux);
    const float v2 = dpp_wave_sum(ft*uy);
    const float v3 = dpp_wave_sum(ft*uz);
    if (lane == 63) {
      part[wave*32 + k*4+0] = v0;
      part[wave*32 + k*4+1] = v1;
      part[wave*32 + k*4+2] = v2;
      part[wave*32 + k*4+3] = v3;
    }
  }
  __syncthreads();
  if (tid < 64) {
    const int tj = tid >> 5, c = tid & 31;
    U[tid] = part[(tj*2+0)*32 + c] + part[(tj*2+1)*32 + c];
  }
  __syncthreads();
  if (tid < 64) {
    const int p = tid >> 2, a = tid & 3;
    float s = 0.f;
    #pragma unroll
    for (int tj = 0; tj < 2; ++tj)
      #pragma unroll
      for (int k = 0; k < 8; ++k)
        s += c_lds[tj*128 + p*8 + k] * U[tj*32 + k*4 + a];
    s *= (1.0f/(float)MM);
    S_lds[tid] = s;
    S_ws[(size_t)bn*64 + tid] = s;
  }
  __syncthreads();
  if (tid < 64) {
    const int p = tid >> 2, q = tid & 3;
    float f = 0.f;
    #pragma unroll
    for (int a = 0; a < 4; ++a) f += S_lds[p*4+a]*S_lds[q*4+a];
    float fs = f, fss = f*f;
    for (int o = 32; o > 0; o >>= 1) { fs += __shfl_down(fs, o); fss += __shfl_down(fss, o); }
    if (tid == 0) { statp[bn*2+0] = fs; statp[bn*2+1] = fss; }
  }
}

/* ---- MFMA bf16 MLP (round-11, verified) ---- */
__global__ __launch_bounds__(256) void k_mlp(
    const float* __restrict__ S_ws, const int* __restrict__ tmap,
    const float* __restrict__ statp,
    const unsigned short* __restrict__ wtb, const unsigned short* __restrict__ wb,
    const float* __restrict__ b0, const float* __restrict__ b1,
    const float* __restrict__ b2, const float* __restrict__ Wout,
    const float* __restrict__ bout,
    float* __restrict__ dfeat_ws, float* __restrict__ out)
{
  __shared__ float sl[MT*64];
  __shared__ float xb[MT*AS0];
  __shared__ float t0b[MT*AS1];
  __shared__ float h1b[MT*AS1];
  __shared__ float dzb[MT*AS1];
  __shared__ float es[MT];
  __shared__ float srd[8];
  __shared__ float muSd[2];
  const int tb = blockIdx.x;
  const int bn0 = tb*MT;
  const int tid = threadIdx.x;
  const int wave = tid >> 6, lane = tid & 63;
  const int quad = lane >> 4, nI = lane & 15;
  const int t = tmap[bn0 & (NN-1)];
  {
    const float4* src = (const float4*)(S_ws + (size_t)bn0*64);
    ((float4*)sl)[tid] = src[tid];
  }
  {
    float fs = 0.f, fss = 0.f;
    #pragma unroll 4
    for (int i = 0; i < 16; ++i) {
      const int e = i*256 + tid;
      const int b = e >> 9;
      const int n = t*512 + (e & 511);
      const float2 v = *(const float2*)&statp[((size_t)(b*NN + n))*2];
      fs += v.x; fss += v.y;
    }
    for (int o = 32; o > 0; o >>= 1) { fs += __shfl_down(fs, o); fss += __shfl_down(fss, o); }
    if ((tid & 63) == 0) { srd[(tid>>6)*2] = fs; srd[(tid>>6)*2+1] = fss; }
  }
  __syncthreads();
  if (tid == 0) {
    const float S1 = srd[0]+srd[2]+srd[4]+srd[6];
    const float S2 = srd[1]+srd[3]+srd[5]+srd[7];
    const float cnt = 512.0f * (float)BB * (float)NFEAT;
    const float mu = S1/cnt;
    const float var = (S2 - cnt*mu*mu)/(cnt - 1.0f);
    muSd[0] = mu; muSd[1] = sqrtf(fmaxf(var, 1e-20f));
  }
  __syncthreads();
  const float mu = muSd[0];
  const float inv_sd = 1.0f/muSd[1];
  #pragma unroll
  for (int i = 0; i < 4; ++i) {
    const int e = i*256 + tid;
    const int at = e >> 6, f = e & 63;
    const int p = f >> 2, q = f & 3;
    const float* Sr = &sl[at*64];
    float s = 0.f;
    #pragma unroll
    for (int a = 0; a < 4; ++a) s += Sr[p*4+a]*Sr[q*4+a];
    xb[at*AS0 + f] = (s - mu)*inv_sd;
  }
  __syncthreads();

  const int c0 = (wave*2+0)*16 + nI;
  const int c1 = (wave*2+1)*16 + nI;
  f4 acc0, acc1;

  /* L0 */
  acc0 = splat4(b0[t*HH + c0]);
  acc1 = splat4(b0[t*HH + c1]);
  {
    const unsigned short* B = wtb + WT0_OFF + t*8192;
    #pragma unroll
    for (int s = 0; s < 2; ++s) {
      const bf8 a  = a_frag(&xb[nI*AS0 + s*32 + quad*8]);
      const bf8 bA = *(const bf8*)&B[(size_t)c0*64 + s*32 + quad*8];
      const bf8 bB = *(const bf8*)&B[(size_t)c1*64 + s*32 + quad*8];
      acc0 = __builtin_amdgcn_mfma_f32_16x16x32_bf16(a, bA, acc0, 0, 0, 0);
      acc1 = __builtin_amdgcn_mfma_f32_16x16x32_bf16(a, bB, acc1, 0, 0, 0);
    }
  }
  #pragma unroll
  for (int r = 0; r < 4; ++r) {
    const int row = quad*4 + r;
    t0b[row*AS1 + c0] = ftanh(acc0[r]);
    t0b[row*AS1 + c1] = ftanh(acc1[r]);
  }
  __syncthreads();
  /* L1 */
  acc0 = splat4(b1[t*HH + c0]);
  acc1 = splat4(b1[t*HH + c1]);
  {
    const unsigned short* B = wtb + WT1_OFF + t*16384;
    #pragma unroll
    for (int s = 0; s < 4; ++s) {
      const bf8 a  = a_frag(&t0b[nI*AS1 + s*32 + quad*8]);
      const bf8 bA = *(const bf8*)&B[(size_t)c0*128 + s*32 + quad*8];
      const bf8 bB = *(const bf8*)&B[(size_t)c1*128 + s*32 + quad*8];
      acc0 = __builtin_amdgcn_mfma_f32_16x16x32_bf16(a, bA, acc0, 0, 0, 0);
      acc1 = __builtin_amdgcn_mfma_f32_16x16x32_bf16(a, bB, acc1, 0, 0, 0);
    }
  }
  #pragma unroll
  for (int r = 0; r < 4; ++r) {
    const int row = quad*4 + r;
    h1b[row*AS1 + c0] = ftanh(acc0[r]) + t0b[row*AS1 + c0];
    h1b[row*AS1 + c1] = ftanh(acc1[r]) + t0b[row*AS1 + c1];
  }
  __syncthreads();
  /* L2 */
  acc0 = splat4(b2[t*HH + c0]);
  acc1 = splat4(b2[t*HH + c1]);
  {
    const unsigned short* B = wtb + WT2_OFF + t*16384;
    #pragma unroll
    for (int s = 0; s < 4; ++s) {
      const bf8 a  = a_frag(&h1b[nI*AS1 + s*32 + quad*8]);
      const bf8 bA = *(const bf8*)&B[(size_t)c0*128 + s*32 + quad*8];
      const bf8 bB = *(const bf8*)&B[(size_t)c1*128 + s*32 + quad*8];
      acc0 = __builtin_amdgcn_mfma_f32_16x16x32_bf16(a, bA, acc0, 0, 0, 0);
      acc1 = __builtin_amdgcn_mfma_f32_16x16x32_bf16(a, bB, acc1, 0, 0, 0);
    }
  }
  #pragma unroll
  for (int r = 0; r < 4; ++r) {
    const int row = quad*4 + r;
    dzb[row*AS1 + c0] = acc0[r];
    dzb[row*AS1 + c1] = acc1[r];
  }
  __syncthreads();
  {
    const int at = tid >> 4, cb = (tid & 15)*8;
    const float* wop = Wout + t*HH;
    float ep = 0.f;
    #pragma unroll
    for (int j = 0; j < 8; ++j) {
      const int c = cb + j;
      const float z2 = dzb[at*AS1 + c];
      const float t2 = ftanh(z2);
      const float wo = wop[c];
      ep += (t2 + h1b[at*AS1 + c])*wo;
      dzb[at*AS1 + c] = wo*(1.0f - t2*t2);
    }
    ep += __shfl_down(ep, 8, 16);
    ep += __shfl_down(ep, 4, 16);
    ep += __shfl_down(ep, 2, 16);
    ep += __shfl_down(ep, 1, 16);
    if ((tid & 15) == 0) es[at] = ep;
  }
  __syncthreads();
  if (tid < MT) out[OUT_EI + bn0 + tid] = es[tid] + bout[t];

  /* BGEMM1: dh1 = wo + dz2 @ W2^T */
  {
    const float* wop = Wout + t*HH;
    acc0 = splat4(wop[c0]);
    acc1 = splat4(wop[c1]);
    const unsigned short* B = wb + WT2_OFF + t*16384;
    #pragma unroll
    for (int s = 0; s < 4; ++s) {
      const bf8 a  = a_frag(&dzb[nI*AS1 + s*32 + quad*8]);
      const bf8 bA = *(const bf8*)&B[(size_t)c0*128 + s*32 + quad*8];
      const bf8 bB = *(const bf8*)&B[(size_t)c1*128 + s*32 + quad*8];
      acc0 = __builtin_amdgcn_mfma_f32_16x16x32_bf16(a, bA, acc0, 0, 0, 0);
      acc1 = __builtin_amdgcn_mfma_f32_16x16x32_bf16(a, bB, acc1, 0, 0, 0);
    }
  }
  __syncthreads();
  float dh10[4], dh11[4];
  #pragma unroll
  for (int r = 0; r < 4; ++r) {
    const int row = quad*4 + r;
    dh10[r] = acc0[r]; dh11[r] = acc1[r];
    const float t1a = h1b[row*AS1 + c0] - t0b[row*AS1 + c0];
    const float t1b = h1b[row*AS1 + c1] - t0b[row*AS1 + c1];
    dzb[row*AS1 + c0] = acc0[r]*(1.0f - t1a*t1a);
    dzb[row*AS1 + c1] = acc1[r]*(1.0f - t1b*t1b);
  }
  __syncthreads();
  /* BGEMM2: dh0 = dh1 + dz1 @ W1^T */
  acc0[0]=dh10[0]; acc0[1]=dh10[1]; acc0[2]=dh10[2]; acc0[3]=dh10[3];
  acc1[0]=dh11[0]; acc1[1]=dh11[1]; acc1[2]=dh11[2]; acc1[3]=dh11[3];
  {
    const unsigned short* B = wb + WT1_OFF + t*16384;
    #pragma unroll
    for (int s = 0; s < 4; ++s) {
      const bf8 a  = a_frag(&dzb[nI*AS1 + s*32 + quad*8]);
      const bf8 bA = *(const bf8*)&B[(size_t)c0*128 + s*32 + quad*8];
      const bf8 bB = *(const bf8*)&B[(size_t)c1*128 + s*32 + quad*8];
      acc0 = __builtin_amdgcn_mfma_f32_16x16x32_bf16(a, bA, acc0, 0, 0, 0);
      acc1 = __builtin_amdgcn_mfma_f32_16x16x32_bf16(a, bB, acc1, 0, 0, 0);
    }
  }
  __syncthreads();
  #pragma unroll
  for (int r = 0; r < 4; ++r) {
    const int row = quad*4 + r;
    const float ta = t0b[row*AS1 + c0], tb = t0b[row*AS1 + c1];
    dzb[row*AS1 + c0] = acc0[r]*(1.0f - ta*ta);
    dzb[row*AS1 + c1] = acc1[r]*(1.0f - tb*tb);
  }
  __syncthreads();
  /* BGEMM3: dx = dz0 @ W0^T */
  {
    const int cx = wave*16 + nI;
    acc0 = splat4(0.f);
    const unsigned short* B = wb + WT0_OFF + t*8192;
    #pragma unroll
    for (int s = 0; s < 4; ++s) {
      const bf8 a  = a_frag(&dzb[nI*AS1 + s*32 + quad*8]);
      const bf8 bA = *(const bf8*)&B[(size_t)cx*128 + s*32 + quad*8];
      acc0 = __builtin_amdgcn_mfma_f32_16x16x32_bf16(a, bA, acc0, 0, 0, 0);
    }
    #pragma unroll
    for (int r = 0; r < 4; ++r)
      dfeat_ws[(size_t)(bn0 + quad*4 + r)*64 + cx] = acc0[r]*inv_sd;
  }
}

/* ---- fused backward pair + scatter (round-12, verified) ---- */
__global__ __launch_bounds__(256, 4) void k_bwdsc(
    const float* __restrict__ rvec, const int* __restrict__ nlist,
    const int* __restrict__ tmap, const float* __restrict__ c_param,
    const float* __restrict__ S_ws, const float* __restrict__ dfeat_ws,
    float* __restrict__ fpart_ws, float* __restrict__ virp)
{
  __shared__ float c_lds[256];
  __shared__ float Sb[AT2*64];
  __shared__ float Db[AT2*64];
  __shared__ float dSb[AT2*64];
  __shared__ float Eb[AT2*64];
  __shared__ float fpart[F3];
  __shared__ float wredc[AT2*4*3];
  __shared__ float vred[4*9];
  const int blk = blockIdx.x;          /* b*NG2 + g */
  const int b = blk >> 7;
  const int g = blk & (NG2-1);
  const int n0 = g*AT2;
  const int tid = threadIdx.x;
  const int ti = tmap[n0];             /* type uniform across group (8|512) */
  c_lds[tid] = c_param[ti*256 + tid];
  if (tid < 128) {
    const float4* s4 = (const float4*)(S_ws + ((size_t)b*NN + n0)*64);
    const float4* d4 = (const float4*)(dfeat_ws + ((size_t)b*NN + n0)*64);
    ((float4*)Sb)[tid] = s4[tid];
    ((float4*)Db)[tid] = d4[tid];
  }
  {
    const float4 z4 = {0.f, 0.f, 0.f, 0.f};
    for (int i = tid; i < F3/4; i += 256) ((float4*)fpart)[i] = z4;
  }
  __syncthreads();
  #pragma unroll
  for (int it = 0; it < 2; ++it) {
    const int idx = it*256 + tid;
    const int at = idx >> 6, f = idx & 63;
    const int i = f >> 2, a = f & 3;
    const float* Sr = &Sb[at*64];
    const float* Dr = &Db[at*64];
    float v = 0.f;
    #pragma unroll
    for (int q = 0; q < 4; ++q) v += Dr[i*4+q]*Sr[q*4+a];
    if (i < 4)
      for (int p = 0; p < 16; ++p) v += Dr[p*4+i]*Sr[p*4+a];
    dSb[idx] = v;
  }
  __syncthreads();
  #pragma unroll
  for (int it = 0; it < 2; ++it) {
    const int idx = it*256 + tid;
    const int at = idx >> 6, rem = idx & 63;
    const int tj = rem >> 5, a = (rem >> 3) & 3, k = rem & 7;
    float e = 0.f;
    #pragma unroll
    for (int p = 0; p < 16; ++p) e += dSb[at*64 + p*4 + a]*c_lds[tj*128 + p*8 + k];
    Eb[idx] = e;
  }
  __syncthreads();

  float vir[9];
  #pragma unroll
  for (int i = 0; i < 9; ++i) vir[i] = 0.f;
  const int wave = tid >> 6, lane = tid & 63;
  const int tjm = tid >> 7;
  const float dudr = 2.0f/SPANf;
  const float invM = 1.0f/(float)MM;

  const size_t rowbase = ((size_t)b*NN + n0)*MM;
  float px0, py0, pz0, px1, py1, pz1; int pnl0, pnl1;
  {
    const float* rp0 = rvec + (rowbase + tid)*3;
    const float* rp1 = rvec + (rowbase + MM + tid)*3;
    px0 = rp0[0]; py0 = rp0[1]; pz0 = rp0[2]; pnl0 = nlist[rowbase + tid];
    px1 = rp1[0]; py1 = rp1[1]; pz1 = rp1[2]; pnl1 = nlist[rowbase + MM + tid];
  }
  for (int a0 = 0; a0 < AT2; a0 += 2) {
    const float x0 = px0, y0 = py0, z0 = pz0; const int nl0 = pnl0;
    const float x1 = px1, y1 = py1, z1 = pz1; const int nl1 = pnl1;
    if (a0 + 2 < AT2) {
      const float* rp0 = rvec + (rowbase + (size_t)(a0+2)*MM + tid)*3;
      const float* rp1 = rvec + (rowbase + (size_t)(a0+3)*MM + tid)*3;
      px0 = rp0[0]; py0 = rp0[1]; pz0 = rp0[2];
      pnl0 = nlist[rowbase + (size_t)(a0+2)*MM + tid];
      px1 = rp1[0]; py1 = rp1[1]; pz1 = rp1[2];
      pnl1 = nlist[rowbase + (size_t)(a0+3)*MM + tid];
    }
    float Er0[32], Er1[32];
    {
      const float4* p0 = (const float4*)&Eb[a0*64 + tjm*32];
      const float4* p1 = (const float4*)&Eb[(a0+1)*64 + tjm*32];
      #pragma unroll
      for (int q = 0; q < 8; ++q) {
        const float4 v0 = p0[q], v1 = p1[q];
        Er0[q*4+0]=v0.x; Er0[q*4+1]=v0.y; Er0[q*4+2]=v0.z; Er0[q*4+3]=v0.w;
        Er1[q*4+0]=v1.x; Er1[q*4+1]=v1.y; Er1[q*4+2]=v1.z; Er1[q*4+3]=v1.w;
      }
    }
    const float r_0 = sqrtf(x0*x0 + y0*y0 + z0*z0);
    const float r_1 = sqrtf(x1*x1 + y1*y1 + z1*z1);
    const float ir0 = 1.0f/r_0, ir1 = 1.0f/r_1;
    const float ux0 = x0*ir0, uy0 = y0*ir0, uz0 = z0*ir0;
    const float ux1 = x1*ir1, uy1 = y1*ir1, uz1 = z1*ir1;
    float u0 = 2.0f*(r_0 - RMINf)/SPANf - 1.0f;
    float u1 = 2.0f*(r_1 - RMINf)/SPANf - 1.0f;
    u0 = fminf(fmaxf(u0, -1.0f), 1.0f);
    u1 = fminf(fmaxf(u1, -1.0f), 1.0f);
    float s0a, c0a, s1a, c1a;
    __sincosf(PIf*(r_0 - RMINf)/SPANf, &s0a, &c0a);
    __sincosf(PIf*(r_1 - RMINf)/SPANf, &s1a, &c1a);
    const float fc0 = 0.5f*(c0a + 1.0f), dfc0 = -0.5f*(PIf/SPANf)*s0a;
    const float fc1 = 0.5f*(c1a + 1.0f), dfc1 = -0.5f*(PIf/SPANf)*s1a;
    float ta0[4], tda0[4], ta1[4], tda1[4];
    #pragma unroll
    for (int aa = 0; aa < 4; ++aa) {
      ta0[aa]  = Er0[aa*8] + Er0[aa*8+1]*u0;
      tda0[aa] = Er0[aa*8+1];
      ta1[aa]  = Er1[aa*8] + Er1[aa*8+1]*u1;
      tda1[aa] = Er1[aa*8+1];
    }
    float t0m2 = 1.f, t0m1 = u0, d0m2 = 0.f, d0m1 = 1.f;
    float t1m2 = 1.f, t1m1 = u1, d1m2 = 0.f, d1m1 = 1.f;
    #pragma unroll
    for (int k = 2; k < BETA; ++k) {
      const float tk0 = 2.f*u0*t0m1 - t0m2;
      const float dk0 = 2.f*t0m1 + 2.f*u0*d0m1 - d0m2;
      const float tk1 = 2.f*u1*t1m1 - t1m2;
      const float dk1 = 2.f*t1m1 + 2.f*u1*d1m1 - d1m2;
      #pragma unroll
      for (int aa = 0; aa < 4; ++aa) {
        ta0[aa]  += Er0[aa*8+k]*tk0;
        tda0[aa] += Er0[aa*8+k]*dk0;
        ta1[aa]  += Er1[aa*8+k]*tk1;
        tda1[aa] += Er1[aa*8+k]*dk1;
      }
      t0m2 = t0m1; t0m1 = tk0; d0m2 = d0m1; d0m1 = dk0;
      t1m2 = t1m1; t1m1 = tk1; d1m2 = d1m1; d1m1 = dk1;
    }
    float A0 = dfc0*(ta0[0] + ux0*ta0[1] + uy0*ta0[2] + uz0*ta0[3])
             + fc0*dudr*(tda0[0] + ux0*tda0[1] + uy0*tda0[2] + uz0*tda0[3]);
    float A1 = dfc1*(ta1[0] + ux1*ta1[1] + uy1*ta1[2] + uz1*ta1[3])
             + fc1*dudr*(tda1[0] + ux1*tda1[1] + uy1*tda1[2] + uz1*tda1[3]);
    float q10 = fc0*ta0[1], q20 = fc0*ta0[2], q30 = fc0*ta0[3];
    float q11 = fc1*ta1[1], q21 = fc1*ta1[2], q31 = fc1*ta1[3];
    A0 *= invM; q10 *= invM; q20 *= invM; q30 *= invM;
    A1 *= invM; q11 *= invM; q21 *= invM; q31 *= invM;
    const float qu0 = q10*ux0 + q20*uy0 + q30*uz0;
    const float qu1 = q11*ux1 + q21*uy1 + q31*uz1;
    const float d00 = A0*ux0 + (q10 - qu0*ux0)*ir0;
    const float d01 = A0*uy0 + (q20 - qu0*uy0)*ir0;
    const float d02 = A0*uz0 + (q30 - qu0*uz0)*ir0;
    const float d10 = A1*ux1 + (q11 - qu1*ux1)*ir1;
    const float d11 = A1*uy1 + (q21 - qu1*uy1)*ir1;
    const float d12 = A1*uz1 + (q31 - qu1*uz1)*ir1;
    if (nl0 > 0) {
      const int j = nl0 - 1;
      atomicAdd(&fpart[j*3+0], -d00);
      atomicAdd(&fpart[j*3+1], -d01);
      atomicAdd(&fpart[j*3+2], -d02);
    }
    if (nl1 > 0) {
      const int j = nl1 - 1;
      atomicAdd(&fpart[j*3+0], -d10);
      atomicAdd(&fpart[j*3+1], -d11);
      atomicAdd(&fpart[j*3+2], -d12);
    }
    vir[0] -= x0*d00 + x1*d10; vir[1] -= x0*d01 + x1*d11; vir[2] -= x0*d02 + x1*d12;
    vir[3] -= y0*d00 + y1*d10; vir[4] -= y0*d01 + y1*d11; vir[5] -= y0*d02 + y1*d12;
    vir[6] -= z0*d00 + z1*d10; vir[7] -= z0*d01 + z1*d11; vir[8] -= z0*d02 + z1*d12;
    const float r00 = dpp_wave_sum(d00), r01 = dpp_wave_sum(d01), r02 = dpp_wave_sum(d02);
    const float r10 = dpp_wave_sum(d10), r11 = dpp_wave_sum(d11), r12 = dpp_wave_sum(d12);
    if (lane == 63) {
      wredc[(a0*4 + wave)*3 + 0] = r00;
      wredc[(a0*4 + wave)*3 + 1] = r01;
      wredc[(a0*4 + wave)*3 + 2] = r02;
      wredc[((a0+1)*4 + wave)*3 + 0] = r10;
      wredc[((a0+1)*4 + wave)*3 + 1] = r11;
      wredc[((a0+1)*4 + wave)*3 + 2] = r12;
    }
  }
  #pragma unroll
  for (int i = 0; i < 9; ++i) {
    const float v = dpp_wave_sum(vir[i]);
    if (lane == 63) vred[wave*9 + i] = v;
  }
  __syncthreads();
  if (tid < AT2*3) {
    const int at = tid/3, c = tid - at*3;
    const float v = wredc[(at*4+0)*3+c] + wredc[(at*4+1)*3+c]
                  + wredc[(at*4+2)*3+c] + wredc[(at*4+3)*3+c];
    atomicAdd(&fpart[(n0+at)*3 + c], v);
  }
  if (tid >= 64 && tid < 73) {
    const int i = tid - 64;
    virp[(size_t)blk*9 + i] = vred[i] + vred[9+i] + vred[18+i] + vred[27+i];
  }
  __syncthreads();
  {
    float* dst = fpart_ws + (size_t)blk*F3;
    for (int i = tid; i < F3/4; i += 256)
      ((float4*)dst)[i] = ((float4*)fpart)[i];
  }
}

/* blocks 0..407: force   blocks 408..479: virial   blocks 480..487: Etot */
__global__ __launch_bounds__(256) void k_reduce(
    const float* __restrict__ fpart_ws, const float* __restrict__ virp,
    float* __restrict__ out)
{
  __shared__ float comb[4*64];
  __shared__ float red[4];
  const int tid = threadIdx.x;
  const int blk = blockIdx.x;
  if (blk < 408) {
    const int el = tid & 63, gc = tid >> 6;
    const int e = blk*64 + el;            /* e < 26112 == BB*F3 exactly */
    const int b = e / F3;
    const int i = e - b*F3;
    const float* base = fpart_ws + (size_t)(b*NG2)*F3 + i;
    float s = 0.f;
    #pragma unroll 8
    for (int g = gc*32; g < gc*32 + 32; ++g) s += base[(size_t)g*F3];
    comb[gc*64 + el] = s;
    __syncthreads();
    if (tid < 64)
      out[OUT_FORCE + blk*64 + tid] = comb[tid] + comb[64+tid] + comb[128+tid] + comb[192+tid];
    return;
  }
  if (blk < 480) {
    const int vb = blk - 408;
    const int b = vb / 9, c = vb - (vb/9)*9;
    float v = (tid < NG2) ? virp[((size_t)(b*NG2 + tid))*9 + c] : 0.f;
    for (int o = 32; o > 0; o >>= 1) v += __shfl_down(v, o);
    if ((tid & 63) == 0) red[tid >> 6] = v;
    __syncthreads();
    if (tid == 0) out[OUT_VIR + vb] = red[0] + red[1];
    return;
  }
  const int b = blk - 480;
  float v = 0.f;
  #pragma unroll
  for (int k = 0; k < 4; ++k) v += out[OUT_EI + b*NN + k*256 + tid];
  for (int o = 32; o > 0; o >>= 1) v += __shfl_down(v, o);
  if ((tid & 63) == 0) red[tid >> 6] = v;
  __syncthreads();
  if (tid == 0) out[b] = red[0] + red[1] + red[2] + red[3];
}

extern "C" void kernel_launch(void* const* d_in, const int* in_sizes, int n_in,
                              void* d_out, int out_size, void* d_ws, size_t ws_size,
                              hipStream_t stream)
{
  const int*   nlist = (const int*)d_in[0];
  const int*   tmap  = (const int*)d_in[1];
  const float* rvec  = (const float*)d_in[2];
  const float* cpar  = (const float*)d_in[3];
  const float* W0 = (const float*)d_in[4];
  const float* b0 = (const float*)d_in[5];
  const float* W1 = (const float*)d_in[6];
  const float* b1 = (const float*)d_in[7];
  const float* W2 = (const float*)d_in[8];
  const float* b2 = (const float*)d_in[9];
  const float* Wout = (const float*)d_in[10];
  const float* bout = (const float*)d_in[11];
  float* out = (float*)d_out;
  float* ws = (float*)d_ws;
  float* S_ws   = ws + WS_S;
  float* df_ws  = ws + WS_DF;
  float* fpartw = ws + WS_FP;
  float* statp  = ws + WS_STATP;
  float* virp   = ws + WS_VIRP;
  unsigned short* wtb = (unsigned short*)(ws + WS_WTB);
  unsigned short* wb  = (unsigned short*)(ws + WS_WB);

  k_feat <<<BB*NN + 640, 256, 0, stream>>>(rvec, tmap, cpar, S_ws, statp,
                                           W0, W1, W2, wtb, wb);
  k_mlp  <<<(BB*NN)/MT, 256, 0, stream>>>(S_ws, tmap, statp, wtb, wb,
                                          b0, b1, b2, Wout, bout, df_ws, out);
  k_bwdsc<<<BB*NG2, 256, 0, stream>>>(rvec, nlist, tmap, cpar, S_ws, df_ws,
                                      fpartw, virp);
  k_reduce<<<488, 256, 0, stream>>>(fpartw, virp, out);
}

// Round 14
// 171.418 us; speedup vs baseline: 1.0263x; 1.0263x over previous
//
#include <hip/hip_runtime.h>
#include <math.h>

#define BB 8
#define NN 1024
#define MM 256
#define BETA 8
#define M1 16
#define NFEAT 64
#define HH 128
#define NTOT 1088   /* N + NGHOST */
#define F3 (NTOT*3) /* 3264 */
#define RMINf 0.5f
#define SPANf 5.5f
#define PIf 3.14159265358979323846f

#define OUT_EI 8
#define OUT_FORCE 8200          /* 8 + 8192 */
#define OUT_VIR 34312           /* 8200 + 8*1088*3 */

#define NG2 128                 /* scatter/bwd groups per batch (round-8 optimum) */
#define AT2 (NN/NG2)            /* 8 atoms per fused block */

#define MT 16                   /* atoms per MLP tile */
#define AS0 68                  /* xb stride (64+4), 16B-aligned rows */
#define AS1 132                 /* activation stride (128+4), 16B-aligned rows */

/* workspace float offsets */
#define WS_S     0
#define WS_DF    (WS_S + 8192*64)
#define WS_FP    (WS_DF + 8192*64)       /* fpart partials: 1024*F3 */
#define WS_STATP (WS_FP + BB*NG2*F3)
#define WS_VIRP  (WS_STATP + 8192*2)     /* 1024*9 */
#define WS_WTB   (WS_VIRP + BB*NG2*9)    /* bf16 transposed weights: 81920 shorts */
#define WS_WB    (WS_WTB + 40960)        /* bf16 original weights: 81920 shorts */
#define WT0_OFF  0
#define WT1_OFF  16384
#define WT2_OFF  49152

typedef __attribute__((ext_vector_type(8))) short bf8;
typedef __attribute__((ext_vector_type(4))) float f4;

__device__ __forceinline__ float ftanh(float x) {
  const float e = __expf(2.0f*x);
  return 1.0f - 2.0f/(e + 1.0f);
}
__device__ __forceinline__ short f2bs(float f) {   /* fp32 -> bf16 RNE */
  unsigned u = __float_as_uint(f);
  return (short)((u + 0x7FFFu + ((u >> 16) & 1u)) >> 16);
}
__device__ __forceinline__ bf8 a_frag(const float* p) {  /* 8 consecutive fp32 -> bf16x8 */
  bf8 a;
  #pragma unroll
  for (int i = 0; i < 8; ++i) a[i] = f2bs(p[i]);
  return a;
}
__device__ __forceinline__ f4 splat4(float v) {
  f4 r; r[0] = v; r[1] = v; r[2] = v; r[3] = v; return r;
}
/* wave64 sum via DPP (VALU pipe, no LDS); total lands in lane 63 */
__device__ __forceinline__ float dpp_wave_sum(float x) {
  x += __int_as_float(__builtin_amdgcn_update_dpp(0, __float_as_int(x), 0x111, 0xf, 0xf, true));
  x += __int_as_float(__builtin_amdgcn_update_dpp(0, __float_as_int(x), 0x112, 0xf, 0xf, true));
  x += __int_as_float(__builtin_amdgcn_update_dpp(0, __float_as_int(x), 0x114, 0xf, 0xf, true));
  x += __int_as_float(__builtin_amdgcn_update_dpp(0, __float_as_int(x), 0x118, 0xf, 0xf, true));
  x += __int_as_float(__builtin_amdgcn_update_dpp(0, __float_as_int(x), 0x142, 0xf, 0xf, true));
  x += __int_as_float(__builtin_amdgcn_update_dpp(0, __float_as_int(x), 0x143, 0xf, 0xf, true));
  return x;
}

/* ---- features via U-factorization + bf16 weight prep tail blocks (round-12) ---- */
__global__ __launch_bounds__(256) void k_feat(
    const float* __restrict__ rvec, const int* __restrict__ tmap,
    const float* __restrict__ c_param, float* __restrict__ S_ws,
    float* __restrict__ statp,
    const float* __restrict__ W0, const float* __restrict__ W1,
    const float* __restrict__ W2,
    unsigned short* __restrict__ wtb, unsigned short* __restrict__ wb)
{
  __shared__ float rv[768];
  __shared__ float c_lds[256];
  __shared__ float prod[256*33];
  __shared__ float part[8*32];
  __shared__ float U[2*32];
  __shared__ float S_lds[64];
  const int tid = threadIdx.x;
  if (blockIdx.x >= BB*NN) {
    const int idx = (blockIdx.x - BB*NN)*256 + tid;  /* 0..163839 */
    if (idx < 81920) {
      unsigned short v;
      if (idx < 16384) {
        const int t = idx >> 13, rem = idx & 8191;
        const int j = rem >> 6, f = rem & 63;
        v = (unsigned short)f2bs(W0[t*8192 + f*128 + j]);
      } else if (idx < 49152) {
        const int i = idx - 16384;
        const int t = i >> 14, rem = i & 16383;
        const int j = rem >> 7, f = rem & 127;
        v = (unsigned short)f2bs(W1[t*16384 + f*128 + j]);
      } else {
        const int i = idx - 49152;
        const int t = i >> 14, rem = i & 16383;
        const int j = rem >> 7, f = rem & 127;
        v = (unsigned short)f2bs(W2[t*16384 + f*128 + j]);
      }
      wtb[idx] = v;
    } else {
      const int k = idx - 81920;
      float src;
      if (k < 16384) src = W0[k];
      else if (k < 49152) src = W1[k - 16384];
      else src = W2[k - 49152];
      wb[k] = (unsigned short)f2bs(src);
    }
    return;
  }
  const int bn = blockIdx.x;
  const int n = bn & (NN-1);
  const int ti = tmap[n];
  c_lds[tid] = c_param[ti*256 + tid];
  const float* rb = rvec + (size_t)bn*MM*3;
  rv[tid] = rb[tid]; rv[tid+256] = rb[tid+256]; rv[tid+512] = rb[tid+512];
  __syncthreads();
  const int m = tid;
  const float x = rv[3*m], y = rv[3*m+1], z = rv[3*m+2];
  const float r = sqrtf(x*x + y*y + z*z);
  const float inv_r = 1.0f / r;
  const float ux = x*inv_r, uy = y*inv_r, uz = z*inv_r;
  float u = 2.0f*(r - RMINf)/SPANf - 1.0f;
  u = fminf(fmaxf(u, -1.0f), 1.0f);
  const float fc = 0.5f*(__cosf(PIf*(r - RMINf)/SPANf) + 1.0f);
  float T[BETA];
  T[0] = 1.0f; T[1] = u;
  #pragma unroll
  for (int k = 2; k < BETA; ++k) T[k] = 2.0f*u*T[k-1] - T[k-2];
  float* pr = &prod[m*33];
  #pragma unroll
  for (int k = 0; k < BETA; ++k) {
    const float ft = fc*T[k];
    pr[k*4+0] = ft;
    pr[k*4+1] = ft*ux;
    pr[k*4+2] = ft*uy;
    pr[k*4+3] = ft*uz;
  }
  __syncthreads();
  {
    const int c = tid & 31, oct = tid >> 5;
    const int m0 = oct*32;
    float s = 0.f;
    #pragma unroll 8
    for (int i = 0; i < 32; ++i) s += prod[(m0+i)*33 + c];
    part[oct*32 + c] = s;
  }
  __syncthreads();
  if (tid < 64) {
    const int tj = tid >> 5, c = tid & 31;
    U[tid] = part[(tj*4+0)*32+c] + part[(tj*4+1)*32+c]
           + part[(tj*4+2)*32+c] + part[(tj*4+3)*32+c];
  }
  __syncthreads();
  if (tid < 64) {
    const int p = tid >> 2, a = tid & 3;
    float s = 0.f;
    #pragma unroll
    for (int tj = 0; tj < 2; ++tj)
      #pragma unroll
      for (int k = 0; k < 8; ++k)
        s += c_lds[tj*128 + p*8 + k] * U[tj*32 + k*4 + a];
    s *= (1.0f/(float)MM);
    S_lds[tid] = s;
    S_ws[(size_t)bn*64 + tid] = s;
  }
  __syncthreads();
  if (tid < 64) {
    const int p = tid >> 2, q = tid & 3;
    float f = 0.f;
    #pragma unroll
    for (int a = 0; a < 4; ++a) f += S_lds[p*4+a]*S_lds[q*4+a];
    float fs = f, fss = f*f;
    for (int o = 32; o > 0; o >>= 1) { fs += __shfl_down(fs, o); fss += __shfl_down(fss, o); }
    if (tid == 0) { statp[bn*2+0] = fs; statp[bn*2+1] = fss; }
  }
}

/* ---- MFMA bf16 MLP (round-11, verified) ---- */
__global__ __launch_bounds__(256) void k_mlp(
    const float* __restrict__ S_ws, const int* __restrict__ tmap,
    const float* __restrict__ statp,
    const unsigned short* __restrict__ wtb, const unsigned short* __restrict__ wb,
    const float* __restrict__ b0, const float* __restrict__ b1,
    const float* __restrict__ b2, const float* __restrict__ Wout,
    const float* __restrict__ bout,
    float* __restrict__ dfeat_ws, float* __restrict__ out)
{
  __shared__ float sl[MT*64];
  __shared__ float xb[MT*AS0];
  __shared__ float t0b[MT*AS1];
  __shared__ float h1b[MT*AS1];
  __shared__ float dzb[MT*AS1];
  __shared__ float es[MT];
  __shared__ float srd[8];
  __shared__ float muSd[2];
  const int tb = blockIdx.x;
  const int bn0 = tb*MT;
  const int tid = threadIdx.x;
  const int wave = tid >> 6, lane = tid & 63;
  const int quad = lane >> 4, nI = lane & 15;
  const int t = tmap[bn0 & (NN-1)];
  {
    const float4* src = (const float4*)(S_ws + (size_t)bn0*64);
    ((float4*)sl)[tid] = src[tid];
  }
  {
    float fs = 0.f, fss = 0.f;
    #pragma unroll 4
    for (int i = 0; i < 16; ++i) {
      const int e = i*256 + tid;
      const int b = e >> 9;
      const int n = t*512 + (e & 511);
      const float2 v = *(const float2*)&statp[((size_t)(b*NN + n))*2];
      fs += v.x; fss += v.y;
    }
    for (int o = 32; o > 0; o >>= 1) { fs += __shfl_down(fs, o); fss += __shfl_down(fss, o); }
    if ((tid & 63) == 0) { srd[(tid>>6)*2] = fs; srd[(tid>>6)*2+1] = fss; }
  }
  __syncthreads();
  if (tid == 0) {
    const float S1 = srd[0]+srd[2]+srd[4]+srd[6];
    const float S2 = srd[1]+srd[3]+srd[5]+srd[7];
    const float cnt = 512.0f * (float)BB * (float)NFEAT;
    const float mu = S1/cnt;
    const float var = (S2 - cnt*mu*mu)/(cnt - 1.0f);
    muSd[0] = mu; muSd[1] = sqrtf(fmaxf(var, 1e-20f));
  }
  __syncthreads();
  const float mu = muSd[0];
  const float inv_sd = 1.0f/muSd[1];
  #pragma unroll
  for (int i = 0; i < 4; ++i) {
    const int e = i*256 + tid;
    const int at = e >> 6, f = e & 63;
    const int p = f >> 2, q = f & 3;
    const float* Sr = &sl[at*64];
    float s = 0.f;
    #pragma unroll
    for (int a = 0; a < 4; ++a) s += Sr[p*4+a]*Sr[q*4+a];
    xb[at*AS0 + f] = (s - mu)*inv_sd;
  }
  __syncthreads();

  const int c0 = (wave*2+0)*16 + nI;
  const int c1 = (wave*2+1)*16 + nI;
  f4 acc0, acc1;

  /* L0 */
  acc0 = splat4(b0[t*HH + c0]);
  acc1 = splat4(b0[t*HH + c1]);
  {
    const unsigned short* B = wtb + WT0_OFF + t*8192;
    #pragma unroll
    for (int s = 0; s < 2; ++s) {
      const bf8 a  = a_frag(&xb[nI*AS0 + s*32 + quad*8]);
      const bf8 bA = *(const bf8*)&B[(size_t)c0*64 + s*32 + quad*8];
      const bf8 bB = *(const bf8*)&B[(size_t)c1*64 + s*32 + quad*8];
      acc0 = __builtin_amdgcn_mfma_f32_16x16x32_bf16(a, bA, acc0, 0, 0, 0);
      acc1 = __builtin_amdgcn_mfma_f32_16x16x32_bf16(a, bB, acc1, 0, 0, 0);
    }
  }
  #pragma unroll
  for (int r = 0; r < 4; ++r) {
    const int row = quad*4 + r;
    t0b[row*AS1 + c0] = ftanh(acc0[r]);
    t0b[row*AS1 + c1] = ftanh(acc1[r]);
  }
  __syncthreads();
  /* L1 */
  acc0 = splat4(b1[t*HH + c0]);
  acc1 = splat4(b1[t*HH + c1]);
  {
    const unsigned short* B = wtb + WT1_OFF + t*16384;
    #pragma unroll
    for (int s = 0; s < 4; ++s) {
      const bf8 a  = a_frag(&t0b[nI*AS1 + s*32 + quad*8]);
      const bf8 bA = *(const bf8*)&B[(size_t)c0*128 + s*32 + quad*8];
      const bf8 bB = *(const bf8*)&B[(size_t)c1*128 + s*32 + quad*8];
      acc0 = __builtin_amdgcn_mfma_f32_16x16x32_bf16(a, bA, acc0, 0, 0, 0);
      acc1 = __builtin_amdgcn_mfma_f32_16x16x32_bf16(a, bB, acc1, 0, 0, 0);
    }
  }
  #pragma unroll
  for (int r = 0; r < 4; ++r) {
    const int row = quad*4 + r;
    h1b[row*AS1 + c0] = ftanh(acc0[r]) + t0b[row*AS1 + c0];
    h1b[row*AS1 + c1] = ftanh(acc1[r]) + t0b[row*AS1 + c1];
  }
  __syncthreads();
  /* L2 */
  acc0 = splat4(b2[t*HH + c0]);
  acc1 = splat4(b2[t*HH + c1]);
  {
    const unsigned short* B = wtb + WT2_OFF + t*16384;
    #pragma unroll
    for (int s = 0; s < 4; ++s) {
      const bf8 a  = a_frag(&h1b[nI*AS1 + s*32 + quad*8]);
      const bf8 bA = *(const bf8*)&B[(size_t)c0*128 + s*32 + quad*8];
      const bf8 bB = *(const bf8*)&B[(size_t)c1*128 + s*32 + quad*8];
      acc0 = __builtin_amdgcn_mfma_f32_16x16x32_bf16(a, bA, acc0, 0, 0, 0);
      acc1 = __builtin_amdgcn_mfma_f32_16x16x32_bf16(a, bB, acc1, 0, 0, 0);
    }
  }
  #pragma unroll
  for (int r = 0; r < 4; ++r) {
    const int row = quad*4 + r;
    dzb[row*AS1 + c0] = acc0[r];
    dzb[row*AS1 + c1] = acc1[r];
  }
  __syncthreads();
  {
    const int at = tid >> 4, cb = (tid & 15)*8;
    const float* wop = Wout + t*HH;
    float ep = 0.f;
    #pragma unroll
    for (int j = 0; j < 8; ++j) {
      const int c = cb + j;
      const float z2 = dzb[at*AS1 + c];
      const float t2 = ftanh(z2);
      const float wo = wop[c];
      ep += (t2 + h1b[at*AS1 + c])*wo;
      dzb[at*AS1 + c] = wo*(1.0f - t2*t2);
    }
    ep += __shfl_down(ep, 8, 16);
    ep += __shfl_down(ep, 4, 16);
    ep += __shfl_down(ep, 2, 16);
    ep += __shfl_down(ep, 1, 16);
    if ((tid & 15) == 0) es[at] = ep;
  }
  __syncthreads();
  if (tid < MT) out[OUT_EI + bn0 + tid] = es[tid] + bout[t];

  /* BGEMM1: dh1 = wo + dz2 @ W2^T */
  {
    const float* wop = Wout + t*HH;
    acc0 = splat4(wop[c0]);
    acc1 = splat4(wop[c1]);
    const unsigned short* B = wb + WT2_OFF + t*16384;
    #pragma unroll
    for (int s = 0; s < 4; ++s) {
      const bf8 a  = a_frag(&dzb[nI*AS1 + s*32 + quad*8]);
      const bf8 bA = *(const bf8*)&B[(size_t)c0*128 + s*32 + quad*8];
      const bf8 bB = *(const bf8*)&B[(size_t)c1*128 + s*32 + quad*8];
      acc0 = __builtin_amdgcn_mfma_f32_16x16x32_bf16(a, bA, acc0, 0, 0, 0);
      acc1 = __builtin_amdgcn_mfma_f32_16x16x32_bf16(a, bB, acc1, 0, 0, 0);
    }
  }
  __syncthreads();
  float dh10[4], dh11[4];
  #pragma unroll
  for (int r = 0; r < 4; ++r) {
    const int row = quad*4 + r;
    dh10[r] = acc0[r]; dh11[r] = acc1[r];
    const float t1a = h1b[row*AS1 + c0] - t0b[row*AS1 + c0];
    const float t1b = h1b[row*AS1 + c1] - t0b[row*AS1 + c1];
    dzb[row*AS1 + c0] = acc0[r]*(1.0f - t1a*t1a);
    dzb[row*AS1 + c1] = acc1[r]*(1.0f - t1b*t1b);
  }
  __syncthreads();
  /* BGEMM2: dh0 = dh1 + dz1 @ W1^T */
  acc0[0]=dh10[0]; acc0[1]=dh10[1]; acc0[2]=dh10[2]; acc0[3]=dh10[3];
  acc1[0]=dh11[0]; acc1[1]=dh11[1]; acc1[2]=dh11[2]; acc1[3]=dh11[3];
  {
    const unsigned short* B = wb + WT1_OFF + t*16384;
    #pragma unroll
    for (int s = 0; s < 4; ++s) {
      const bf8 a  = a_frag(&dzb[nI*AS1 + s*32 + quad*8]);
      const bf8 bA = *(const bf8*)&B[(size_t)c0*128 + s*32 + quad*8];
      const bf8 bB = *(const bf8*)&B[(size_t)c1*128 + s*32 + quad*8];
      acc0 = __builtin_amdgcn_mfma_f32_16x16x32_bf16(a, bA, acc0, 0, 0, 0);
      acc1 = __builtin_amdgcn_mfma_f32_16x16x32_bf16(a, bB, acc1, 0, 0, 0);
    }
  }
  __syncthreads();
  #pragma unroll
  for (int r = 0; r < 4; ++r) {
    const int row = quad*4 + r;
    const float ta = t0b[row*AS1 + c0], tb = t0b[row*AS1 + c1];
    dzb[row*AS1 + c0] = acc0[r]*(1.0f - ta*ta);
    dzb[row*AS1 + c1] = acc1[r]*(1.0f - tb*tb);
  }
  __syncthreads();
  /* BGEMM3: dx = dz0 @ W0^T */
  {
    const int cx = wave*16 + nI;
    acc0 = splat4(0.f);
    const unsigned short* B = wb + WT0_OFF + t*8192;
    #pragma unroll
    for (int s = 0; s < 4; ++s) {
      const bf8 a  = a_frag(&dzb[nI*AS1 + s*32 + quad*8]);
      const bf8 bA = *(const bf8*)&B[(size_t)cx*128 + s*32 + quad*8];
      acc0 = __builtin_amdgcn_mfma_f32_16x16x32_bf16(a, bA, acc0, 0, 0, 0);
    }
    #pragma unroll
    for (int r = 0; r < 4; ++r)
      dfeat_ws[(size_t)(bn0 + quad*4 + r)*64 + cx] = acc0[r]*inv_sd;
  }
}

/* ---- fused backward pair + scatter (round-12, verified) ---- */
__global__ __launch_bounds__(256, 4) void k_bwdsc(
    const float* __restrict__ rvec, const int* __restrict__ nlist,
    const int* __restrict__ tmap, const float* __restrict__ c_param,
    const float* __restrict__ S_ws, const float* __restrict__ dfeat_ws,
    float* __restrict__ fpart_ws, float* __restrict__ virp)
{
  __shared__ float c_lds[256];
  __shared__ float Sb[AT2*64];
  __shared__ float Db[AT2*64];
  __shared__ float dSb[AT2*64];
  __shared__ float Eb[AT2*64];
  __shared__ float fpart[F3];
  __shared__ float wredc[AT2*4*3];
  __shared__ float vred[4*9];
  const int blk = blockIdx.x;          /* b*NG2 + g */
  const int b = blk >> 7;
  const int g = blk & (NG2-1);
  const int n0 = g*AT2;
  const int tid = threadIdx.x;
  const int ti = tmap[n0];             /* type uniform across group (8|512) */
  c_lds[tid] = c_param[ti*256 + tid];
  if (tid < 128) {
    const float4* s4 = (const float4*)(S_ws + ((size_t)b*NN + n0)*64);
    const float4* d4 = (const float4*)(dfeat_ws + ((size_t)b*NN + n0)*64);
    ((float4*)Sb)[tid] = s4[tid];
    ((float4*)Db)[tid] = d4[tid];
  }
  {
    const float4 z4 = {0.f, 0.f, 0.f, 0.f};
    for (int i = tid; i < F3/4; i += 256) ((float4*)fpart)[i] = z4;
  }
  __syncthreads();
  #pragma unroll
  for (int it = 0; it < 2; ++it) {
    const int idx = it*256 + tid;
    const int at = idx >> 6, f = idx & 63;
    const int i = f >> 2, a = f & 3;
    const float* Sr = &Sb[at*64];
    const float* Dr = &Db[at*64];
    float v = 0.f;
    #pragma unroll
    for (int q = 0; q < 4; ++q) v += Dr[i*4+q]*Sr[q*4+a];
    if (i < 4)
      for (int p = 0; p < 16; ++p) v += Dr[p*4+i]*Sr[p*4+a];
    dSb[idx] = v;
  }
  __syncthreads();
  #pragma unroll
  for (int it = 0; it < 2; ++it) {
    const int idx = it*256 + tid;
    const int at = idx >> 6, rem = idx & 63;
    const int tj = rem >> 5, a = (rem >> 3) & 3, k = rem & 7;
    float e = 0.f;
    #pragma unroll
    for (int p = 0; p < 16; ++p) e += dSb[at*64 + p*4 + a]*c_lds[tj*128 + p*8 + k];
    Eb[idx] = e;
  }
  __syncthreads();

  float vir[9];
  #pragma unroll
  for (int i = 0; i < 9; ++i) vir[i] = 0.f;
  const int wave = tid >> 6, lane = tid & 63;
  const int tjm = tid >> 7;
  const float dudr = 2.0f/SPANf;
  const float invM = 1.0f/(float)MM;

  const size_t rowbase = ((size_t)b*NN + n0)*MM;
  float px0, py0, pz0, px1, py1, pz1; int pnl0, pnl1;
  {
    const float* rp0 = rvec + (rowbase + tid)*3;
    const float* rp1 = rvec + (rowbase + MM + tid)*3;
    px0 = rp0[0]; py0 = rp0[1]; pz0 = rp0[2]; pnl0 = nlist[rowbase + tid];
    px1 = rp1[0]; py1 = rp1[1]; pz1 = rp1[2]; pnl1 = nlist[rowbase + MM + tid];
  }
  for (int a0 = 0; a0 < AT2; a0 += 2) {
    const float x0 = px0, y0 = py0, z0 = pz0; const int nl0 = pnl0;
    const float x1 = px1, y1 = py1, z1 = pz1; const int nl1 = pnl1;
    if (a0 + 2 < AT2) {
      const float* rp0 = rvec + (rowbase + (size_t)(a0+2)*MM + tid)*3;
      const float* rp1 = rvec + (rowbase + (size_t)(a0+3)*MM + tid)*3;
      px0 = rp0[0]; py0 = rp0[1]; pz0 = rp0[2];
      pnl0 = nlist[rowbase + (size_t)(a0+2)*MM + tid];
      px1 = rp1[0]; py1 = rp1[1]; pz1 = rp1[2];
      pnl1 = nlist[rowbase + (size_t)(a0+3)*MM + tid];
    }
    float Er0[32], Er1[32];
    {
      const float4* p0 = (const float4*)&Eb[a0*64 + tjm*32];
      const float4* p1 = (const float4*)&Eb[(a0+1)*64 + tjm*32];
      #pragma unroll
      for (int q = 0; q < 8; ++q) {
        const float4 v0 = p0[q], v1 = p1[q];
        Er0[q*4+0]=v0.x; Er0[q*4+1]=v0.y; Er0[q*4+2]=v0.z; Er0[q*4+3]=v0.w;
        Er1[q*4+0]=v1.x; Er1[q*4+1]=v1.y; Er1[q*4+2]=v1.z; Er1[q*4+3]=v1.w;
      }
    }
    const float r_0 = sqrtf(x0*x0 + y0*y0 + z0*z0);
    const float r_1 = sqrtf(x1*x1 + y1*y1 + z1*z1);
    const float ir0 = 1.0f/r_0, ir1 = 1.0f/r_1;
    const float ux0 = x0*ir0, uy0 = y0*ir0, uz0 = z0*ir0;
    const float ux1 = x1*ir1, uy1 = y1*ir1, uz1 = z1*ir1;
    float u0 = 2.0f*(r_0 - RMINf)/SPANf - 1.0f;
    float u1 = 2.0f*(r_1 - RMINf)/SPANf - 1.0f;
    u0 = fminf(fmaxf(u0, -1.0f), 1.0f);
    u1 = fminf(fmaxf(u1, -1.0f), 1.0f);
    float s0a, c0a, s1a, c1a;
    __sincosf(PIf*(r_0 - RMINf)/SPANf, &s0a, &c0a);
    __sincosf(PIf*(r_1 - RMINf)/SPANf, &s1a, &c1a);
    const float fc0 = 0.5f*(c0a + 1.0f), dfc0 = -0.5f*(PIf/SPANf)*s0a;
    const float fc1 = 0.5f*(c1a + 1.0f), dfc1 = -0.5f*(PIf/SPANf)*s1a;
    float ta0[4], tda0[4], ta1[4], tda1[4];
    #pragma unroll
    for (int aa = 0; aa < 4; ++aa) {
      ta0[aa]  = Er0[aa*8] + Er0[aa*8+1]*u0;
      tda0[aa] = Er0[aa*8+1];
      ta1[aa]  = Er1[aa*8] + Er1[aa*8+1]*u1;
      tda1[aa] = Er1[aa*8+1];
    }
    float t0m2 = 1.f, t0m1 = u0, d0m2 = 0.f, d0m1 = 1.f;
    float t1m2 = 1.f, t1m1 = u1, d1m2 = 0.f, d1m1 = 1.f;
    #pragma unroll
    for (int k = 2; k < BETA; ++k) {
      const float tk0 = 2.f*u0*t0m1 - t0m2;
      const float dk0 = 2.f*t0m1 + 2.f*u0*d0m1 - d0m2;
      const float tk1 = 2.f*u1*t1m1 - t1m2;
      const float dk1 = 2.f*t1m1 + 2.f*u1*d1m1 - d1m2;
      #pragma unroll
      for (int aa = 0; aa < 4; ++aa) {
        ta0[aa]  += Er0[aa*8+k]*tk0;
        tda0[aa] += Er0[aa*8+k]*dk0;
        ta1[aa]  += Er1[aa*8+k]*tk1;
        tda1[aa] += Er1[aa*8+k]*dk1;
      }
      t0m2 = t0m1; t0m1 = tk0; d0m2 = d0m1; d0m1 = dk0;
      t1m2 = t1m1; t1m1 = tk1; d1m2 = d1m1; d1m1 = dk1;
    }
    float A0 = dfc0*(ta0[0] + ux0*ta0[1] + uy0*ta0[2] + uz0*ta0[3])
             + fc0*dudr*(tda0[0] + ux0*tda0[1] + uy0*tda0[2] + uz0*tda0[3]);
    float A1 = dfc1*(ta1[0] + ux1*ta1[1] + uy1*ta1[2] + uz1*ta1[3])
             + fc1*dudr*(tda1[0] + ux1*tda1[1] + uy1*tda1[2] + uz1*tda1[3]);
    float q10 = fc0*ta0[1], q20 = fc0*ta0[2], q30 = fc0*ta0[3];
    float q11 = fc1*ta1[1], q21 = fc1*ta1[2], q31 = fc1*ta1[3];
    A0 *= invM; q10 *= invM; q20 *= invM; q30 *= invM;
    A1 *= invM; q11 *= invM; q21 *= invM; q31 *= invM;
    const float qu0 = q10*ux0 + q20*uy0 + q30*uz0;
    const float qu1 = q11*ux1 + q21*uy1 + q31*uz1;
    const float d00 = A0*ux0 + (q10 - qu0*ux0)*ir0;
    const float d01 = A0*uy0 + (q20 - qu0*uy0)*ir0;
    const float d02 = A0*uz0 + (q30 - qu0*uz0)*ir0;
    const float d10 = A1*ux1 + (q11 - qu1*ux1)*ir1;
    const float d11 = A1*uy1 + (q21 - qu1*uy1)*ir1;
    const float d12 = A1*uz1 + (q31 - qu1*uz1)*ir1;
    if (nl0 > 0) {
      const int j = nl0 - 1;
      atomicAdd(&fpart[j*3+0], -d00);
      atomicAdd(&fpart[j*3+1], -d01);
      atomicAdd(&fpart[j*3+2], -d02);
    }
    if (nl1 > 0) {
      const int j = nl1 - 1;
      atomicAdd(&fpart[j*3+0], -d10);
      atomicAdd(&fpart[j*3+1], -d11);
      atomicAdd(&fpart[j*3+2], -d12);
    }
    vir[0] -= x0*d00 + x1*d10; vir[1] -= x0*d01 + x1*d11; vir[2] -= x0*d02 + x1*d12;
    vir[3] -= y0*d00 + y1*d10; vir[4] -= y0*d01 + y1*d11; vir[5] -= y0*d02 + y1*d12;
    vir[6] -= z0*d00 + z1*d10; vir[7] -= z0*d01 + z1*d11; vir[8] -= z0*d02 + z1*d12;
    const float r00 = dpp_wave_sum(d00), r01 = dpp_wave_sum(d01), r02 = dpp_wave_sum(d02);
    const float r10 = dpp_wave_sum(d10), r11 = dpp_wave_sum(d11), r12 = dpp_wave_sum(d12);
    if (lane == 63) {
      wredc[(a0*4 + wave)*3 + 0] = r00;
      wredc[(a0*4 + wave)*3 + 1] = r01;
      wredc[(a0*4 + wave)*3 + 2] = r02;
      wredc[((a0+1)*4 + wave)*3 + 0] = r10;
      wredc[((a0+1)*4 + wave)*3 + 1] = r11;
      wredc[((a0+1)*4 + wave)*3 + 2] = r12;
    }
  }
  #pragma unroll
  for (int i = 0; i < 9; ++i) {
    const float v = dpp_wave_sum(vir[i]);
    if (lane == 63) vred[wave*9 + i] = v;
  }
  __syncthreads();
  if (tid < AT2*3) {
    const int at = tid/3, c = tid - at*3;
    const float v = wredc[(at*4+0)*3+c] + wredc[(at*4+1)*3+c]
                  + wredc[(at*4+2)*3+c] + wredc[(at*4+3)*3+c];
    atomicAdd(&fpart[(n0+at)*3 + c], v);
  }
  if (tid >= 64 && tid < 73) {
    const int i = tid - 64;
    virp[(size_t)blk*9 + i] = vred[i] + vred[9+i] + vred[18+i] + vred[27+i];
  }
  __syncthreads();
  {
    float* dst = fpart_ws + (size_t)blk*F3;
    for (int i = tid; i < F3/4; i += 256)
      ((float4*)dst)[i] = ((float4*)fpart)[i];
  }
}

/* blocks 0..407: force   blocks 408..479: virial   blocks 480..487: Etot */
__global__ __launch_bounds__(256) void k_reduce(
    const float* __restrict__ fpart_ws, const float* __restrict__ virp,
    float* __restrict__ out)
{
  __shared__ float comb[4*64];
  __shared__ float red[4];
  const int tid = threadIdx.x;
  const int blk = blockIdx.x;
  if (blk < 408) {
    const int el = tid & 63, gc = tid >> 6;
    const int e = blk*64 + el;            /* e < 26112 == BB*F3 exactly */
    const int b = e / F3;
    const int i = e - b*F3;
    const float* base = fpart_ws + (size_t)(b*NG2)*F3 + i;
    float s = 0.f;
    #pragma unroll 8
    for (int g = gc*32; g < gc*32 + 32; ++g) s += base[(size_t)g*F3];
    comb[gc*64 + el] = s;
    __syncthreads();
    if (tid < 64)
      out[OUT_FORCE + blk*64 + tid] = comb[tid] + comb[64+tid] + comb[128+tid] + comb[192+tid];
    return;
  }
  if (blk < 480) {
    const int vb = blk - 408;
    const int b = vb / 9, c = vb - (vb/9)*9;
    float v = (tid < NG2) ? virp[((size_t)(b*NG2 + tid))*9 + c] : 0.f;
    for (int o = 32; o > 0; o >>= 1) v += __shfl_down(v, o);
    if ((tid & 63) == 0) red[tid >> 6] = v;
    __syncthreads();
    if (tid == 0) out[OUT_VIR + vb] = red[0] + red[1];
    return;
  }
  const int b = blk - 480;
  float v = 0.f;
  #pragma unroll
  for (int k = 0; k < 4; ++k) v += out[OUT_EI + b*NN + k*256 + tid];
  for (int o = 32; o > 0; o >>= 1) v += __shfl_down(v, o);
  if ((tid & 63) == 0) red[tid >> 6] = v;
  __syncthreads();
  if (tid == 0) out[b] = red[0] + red[1] + red[2] + red[3];
}

extern "C" void kernel_launch(void* const* d_in, const int* in_sizes, int n_in,
                              void* d_out, int out_size, void* d_ws, size_t ws_size,
                              hipStream_t stream)
{
  const int*   nlist = (const int*)d_in[0];
  const int*   tmap  = (const int*)d_in[1];
  const float* rvec  = (const float*)d_in[2];
  const float* cpar  = (const float*)d_in[3];
  const float* W0 = (const float*)d_in[4];
  const float* b0 = (const float*)d_in[5];
  const float* W1 = (const float*)d_in[6];
  const float* b1 = (const float*)d_in[7];
  const float* W2 = (const float*)d_in[8];
  const float* b2 = (const float*)d_in[9];
  const float* Wout = (const float*)d_in[10];
  const float* bout = (const float*)d_in[11];
  float* out = (float*)d_out;
  float* ws = (float*)d_ws;
  float* S_ws   = ws + WS_S;
  float* df_ws  = ws + WS_DF;
  float* fpartw = ws + WS_FP;
  float* statp  = ws + WS_STATP;
  float* virp   = ws + WS_VIRP;
  unsigned short* wtb = (unsigned short*)(ws + WS_WTB);
  unsigned short* wb  = (unsigned short*)(ws + WS_WB);

  k_feat <<<BB*NN + 640, 256, 0, stream>>>(rvec, tmap, cpar, S_ws, statp,
                                           W0, W1, W2, wtb, wb);
  k_mlp  <<<(BB*NN)/MT, 256, 0, stream>>>(S_ws, tmap, statp, wtb, wb,
                                          b0, b1, b2, Wout, bout, df_ws, out);
  k_bwdsc<<<BB*NG2, 256, 0, stream>>>(rvec, nlist, tmap, cpar, S_ws, df_ws,
                                      fpartw, virp);
  k_reduce<<<488, 256, 0, stream>>>(fpartw, virp, out);
}